// Round 9
// baseline (536.518 us; speedup 1.0000x reference)
//
#include <hip/hip_runtime.h>
#include <math.h>

typedef unsigned short u16;
typedef unsigned int u32;

typedef float  floatx4 __attribute__((ext_vector_type(4)));
typedef short  shortx8 __attribute__((ext_vector_type(8)));

#define S_LEN 2048
#define E_DIM 1024
#define H_DIM 1024
#define V_DIM 32000

// d_out offsets (fp32 elements)
#define OUT_LOG 0
#define OUT_H   32000
#define OUT_C   33024
#define OUT_XT  34048
#define OUT_W   35072

// ws layout (floats)
#define WS_UB     0
#define WS_SCORES 1024
#define WS_CTX    3072
#define WS_EXPSUM 4097
#define WS_BAR    4100                    // u32 grid-barrier counter
#define WS_ENC16  4608                    // 2048x1024 bf16 = 1048576 floats
#define WS_W16    (4608 + 1048576)       // 1024x1024 bf16 = 524288 floats

__device__ __forceinline__ u16 f2bf_fast(float f) {
    union { float f; u32 i; } v; v.f = f;
    return (u16)((v.i + 0x8000u) >> 16);
}
__device__ __forceinline__ float red16_sum(float x) {
    #pragma unroll
    for (int m = 1; m <= 8; m <<= 1) x += __shfl_xor(x, m, 64);
    return x;
}
__device__ __forceinline__ float wave_sum(float x) {
    #pragma unroll
    for (int m = 32; m >= 1; m >>= 1) x += __shfl_xor(x, m, 64);
    return x;
}
__device__ __forceinline__ float wave_max(float x) {
    #pragma unroll
    for (int m = 32; m >= 1; m >>= 1) x = fmaxf(x, __shfl_xor(x, m, 64));
    return x;
}
__device__ __forceinline__ float dot4(float4 a, float4 b) {
    return a.x * b.x + a.y * b.y + a.z * b.z + a.w * b.w;
}
__device__ __forceinline__ void cvt8(u16* t, float4 a, float4 b) {
    t[0] = f2bf_fast(a.x); t[1] = f2bf_fast(a.y);
    t[2] = f2bf_fast(a.z); t[3] = f2bf_fast(a.w);
    t[4] = f2bf_fast(b.x); t[5] = f2bf_fast(b.y);
    t[6] = f2bf_fast(b.z); t[7] = f2bf_fast(b.w);
}

// Grid-wide barrier: monotonic counter, barrier i waits for cnt >= i*NB.
// Safe iff all blocks co-resident (grid 256, LDS 30.7KB -> 5 blocks/CU cap).
// Device-scope atomics + threadfence handle cross-XCD L2 per guide G16.
__device__ __forceinline__ void grid_bar(u32* cnt, u32 target) {
    __threadfence();
    __syncthreads();
    if (threadIdx.x == 0) {
        __hip_atomic_fetch_add(cnt, 1u, __ATOMIC_ACQ_REL, __HIP_MEMORY_SCOPE_AGENT);
        while (__hip_atomic_load(cnt, __ATOMIC_ACQUIRE, __HIP_MEMORY_SCOPE_AGENT) < target)
            __builtin_amdgcn_s_sleep(8);
    }
    __syncthreads();
    __threadfence();
}

// ---------------- K1: LSTM cell -----------------------------------------
// block = one hidden unit j; wave g = gate row g*H+j, full 64-lane dot.
// grid 1024 x 256 -> 16 waves/CU. Also zeroes the grid-barrier counter.
__global__ __launch_bounds__(256) void k_lstm(
    const float* __restrict__ last_ctx, const int* __restrict__ word,
    const float* __restrict__ emb, const float* __restrict__ h0,
    const float* __restrict__ c0,
    const float* __restrict__ W_ih, const float* __restrict__ b_ih,
    const float* __restrict__ W_hh, const float* __restrict__ b_hh,
    float* __restrict__ out_h, float* __restrict__ out_c,
    float* __restrict__ wsf)
{
    __shared__ float gsh[4];
    int tid = threadIdx.x;
    if (blockIdx.x == 0 && tid == 0)
        __hip_atomic_store((u32*)(wsf + WS_BAR), 0u, __ATOMIC_RELAXED,
                           __HIP_MEMORY_SCOPE_AGENT);
    int g = tid >> 6, l = tid & 63;
    int j = blockIdx.x;
    int row = g * H_DIM + j;
    const float* embrow = emb + (size_t)word[0] * E_DIM;
    const float* wrow = W_ih + (size_t)row * (E_DIM + H_DIM);
    const float* hrow = W_hh + (size_t)row * H_DIM;
    int c4 = l * 4;

    float s = 0.f;
    #pragma unroll
    for (int it = 0; it < 4; ++it) {            // lstm_in cols [0,1024): last_ctx
        int col = it * 256 + c4;
        s += dot4(*(const float4*)(wrow + col), *(const float4*)(last_ctx + col));
    }
    #pragma unroll
    for (int it = 0; it < 4; ++it) {            // lstm_in cols [1024,2048): emb
        int col = it * 256 + c4;
        s += dot4(*(const float4*)(wrow + 1024 + col), *(const float4*)(embrow + col));
    }
    #pragma unroll
    for (int it = 0; it < 4; ++it) {            // W_hh @ h0
        int col = it * 256 + c4;
        s += dot4(*(const float4*)(hrow + col), *(const float4*)(h0 + col));
    }
    s = wave_sum(s);
    if (l == 0) gsh[g] = s + b_ih[row] + b_hh[row];
    __syncthreads();
    if (tid == 0) {
        float gi = 1.f / (1.f + expf(-gsh[0]));
        float gf = 1.f / (1.f + expf(-gsh[1]));
        float gg = tanhf(gsh[2]);
        float go = 1.f / (1.f + expf(-gsh[3]));
        float c = gf * c0[j] + gi * gg;
        float h = go * tanhf(c);
        out_h[j] = h;
        out_c[j] = c;
    }
}

// ---------------- K2: fused attention (uproj|scores|softmax+ctx|xt) -----
// grid 256 x 256, 4 phases separated by grid barriers.
#define LDS_P 40
__global__ __launch_bounds__(256) void k_att_fused(
    const float* __restrict__ W_att, const float* __restrict__ b_att,
    const float* __restrict__ out_h, const float* __restrict__ enc,
    const float* __restrict__ vvec,
    const float* __restrict__ W_ah, const float* __restrict__ b_ah,
    float* __restrict__ out_w, float* __restrict__ out_xt,
    float* __restrict__ wsf)
{
    __shared__ u16 lds_a[2][128 * LDS_P];   // enc tile: 128 s x 32 e
    __shared__ u16 lds_b[2][64 * LDS_P];    // W tile: 64 r x 32 e
    __shared__ float red[4];
    __shared__ float w_lds[8];
    __shared__ float bM, bS;

    int tid = threadIdx.x;
    int b = blockIdx.x;
    u32* bar = (u32*)(wsf + WS_BAR);
    u16* enc16 = (u16*)(wsf + WS_ENC16);
    u16* w16   = (u16*)(wsf + WS_W16);

    // ================= phase 1: ub rows + zero scratch + bf16 pack ======
    {
        int gid = b * 256 + tid;
        if (gid < S_LEN) wsf[WS_SCORES + gid] = 0.f;
        else if (gid < S_LEN + E_DIM) wsf[WS_CTX + gid - S_LEN] = 0.f;
        else if (gid == S_LEN + E_DIM) wsf[WS_EXPSUM] = 0.f;

        int w = tid >> 6, l = tid & 63;
        int r = b * 4 + w;
        const float* wrow = W_att + (size_t)r * (E_DIM + H_DIM);
        int c4 = l * 4;
        float s = 0.f;
        #pragma unroll
        for (int it = 0; it < 4; ++it) {
            int col = it * 256 + c4;
            s += dot4(*(const float4*)(wrow + col), *(const float4*)(out_h + col));
        }
        s = wave_sum(s);
        if (l == 0) wsf[WS_UB + r] = s + b_att[r];

        {   // enc -> bf16: 8 rows/block, 32 floats/thread
            int row = b * 8 + (tid >> 5);
            int col = (tid & 31) * 32;
            const float* src = enc + (size_t)row * E_DIM + col;
            u16 t[32];
            #pragma unroll
            for (int m = 0; m < 32; m += 8) {
                float4 x = *(const float4*)(src + m);
                float4 y = *(const float4*)(src + m + 4);
                cvt8(t + m, x, y);
            }
            uint4* dst = (uint4*)(enc16 + (size_t)row * E_DIM + col);
            #pragma unroll
            for (int m = 0; m < 4; ++m) dst[m] = *(uint4*)(t + m * 8);
        }
        {   // W_att[:, H:H+E] -> bf16: 4 rows/block, 16 floats/thread
            int row = b * 4 + (tid >> 6);
            int col = (tid & 63) * 16;
            const float* src = W_att + (size_t)row * (E_DIM + H_DIM) + H_DIM + col;
            u16 t[16];
            float4 x0 = *(const float4*)(src);
            float4 x1 = *(const float4*)(src + 4);
            float4 x2 = *(const float4*)(src + 8);
            float4 x3 = *(const float4*)(src + 12);
            cvt8(t, x0, x1); cvt8(t + 8, x2, x3);
            uint4* dst = (uint4*)(w16 + (size_t)row * E_DIM + col);
            dst[0] = *(uint4*)(t);
            dst[1] = *(uint4*)(t + 8);
        }
    }

    grid_bar(bar, 256);

    // ================= phase 2: scores GEMM (bf16, MFMA) ================
    {
        const float* ws_ub = wsf + WS_UB;
        float* ws_scores = wsf + WS_SCORES;
        int w = tid >> 6, l = tid & 63;
        int s0 = (b & 15) * 128;
        int r0 = (b >> 4) * 64;
        int lrow = l & 15, lq = l >> 4;

        int arow = tid >> 1, acol = (tid & 1) * 16;
        int brow = tid >> 2, bcol = (tid & 3) * 8;
        const u16* pa_base = enc16 + (size_t)(s0 + arow) * E_DIM + acol;
        const u16* pb_base = w16 + (size_t)(r0 + brow) * E_DIM + bcol;

        floatx4 acc[2][4];
        #pragma unroll
        for (int sf = 0; sf < 2; ++sf)
            #pragma unroll
            for (int i = 0; i < 4; ++i) acc[sf][i] = (floatx4)0.f;

        {
            uint4 a0 = *(const uint4*)(pa_base);
            uint4 a1 = *(const uint4*)(pa_base + 8);
            uint4 b0 = *(const uint4*)(pb_base);
            *(uint4*)&lds_a[0][arow * LDS_P + acol]     = a0;
            *(uint4*)&lds_a[0][arow * LDS_P + acol + 8] = a1;
            *(uint4*)&lds_b[0][brow * LDS_P + bcol]     = b0;
        }
        __syncthreads();

        int cur = 0;
        for (int kc = 0; kc < 32; ++kc) {
            uint4 nA0, nA1, nB0;
            if (kc < 31) {
                const u16* pa = pa_base + (kc + 1) * 32;
                nA0 = *(const uint4*)(pa);
                nA1 = *(const uint4*)(pa + 8);
                nB0 = *(const uint4*)(pb_base + (kc + 1) * 32);
            }

            shortx8 afrag0 = *(const shortx8*)&lds_a[cur][(w * 32 + lrow) * LDS_P + lq * 8];
            shortx8 afrag1 = *(const shortx8*)&lds_a[cur][(w * 32 + 16 + lrow) * LDS_P + lq * 8];
            #pragma unroll
            for (int rc = 0; rc < 4; ++rc) {
                shortx8 bfrag = *(const shortx8*)&lds_b[cur][(rc * 16 + lrow) * LDS_P + lq * 8];
                acc[0][rc] = __builtin_amdgcn_mfma_f32_16x16x32_bf16(afrag0, bfrag, acc[0][rc], 0, 0, 0);
                acc[1][rc] = __builtin_amdgcn_mfma_f32_16x16x32_bf16(afrag1, bfrag, acc[1][rc], 0, 0, 0);
            }

            if (kc < 31) {
                int nb = cur ^ 1;
                *(uint4*)&lds_a[nb][arow * LDS_P + acol]     = nA0;
                *(uint4*)&lds_a[nb][arow * LDS_P + acol + 8] = nA1;
                *(uint4*)&lds_b[nb][brow * LDS_P + bcol]     = nB0;
            }
            __syncthreads();
            cur ^= 1;
        }

        // C layout: col = lane&15 (r), row = (lane>>4)*4 + reg (s)
        float part[2][4] = {{0.f,0.f,0.f,0.f},{0.f,0.f,0.f,0.f}};
        #pragma unroll
        for (int rc = 0; rc < 4; ++rc) {
            int r = r0 + rc * 16 + lrow;
            float ubr = ws_ub[r];
            float vr  = vvec[r];
            #pragma unroll
            for (int sf = 0; sf < 2; ++sf)
                #pragma unroll
                for (int reg = 0; reg < 4; ++reg)
                    part[sf][reg] += tanhf(acc[sf][rc][reg] + ubr) * vr;
        }
        #pragma unroll
        for (int m = 1; m <= 8; m <<= 1)
            #pragma unroll
            for (int sf = 0; sf < 2; ++sf)
                #pragma unroll
                for (int reg = 0; reg < 4; ++reg)
                    part[sf][reg] += __shfl_xor(part[sf][reg], m, 64);
        if (lrow == 0) {
            #pragma unroll
            for (int sf = 0; sf < 2; ++sf) {
                int sbase = s0 + w * 32 + sf * 16 + lq * 4;
                #pragma unroll
                for (int reg = 0; reg < 4; ++reg)
                    atomicAdd(&ws_scores[sbase + reg], part[sf][reg]);
            }
        }
    }

    grid_bar(bar, 512);

    // ================= phase 3: softmax + context (8 s-rows/block) ======
    {
        const float* ws_scores = wsf + WS_SCORES;
        float* ws_ctx = wsf + WS_CTX;
        float4 sa = *(const float4*)(ws_scores + tid * 8);
        float4 sb = *(const float4*)(ws_scores + tid * 8 + 4);
        float m = fmaxf(fmaxf(fmaxf(sa.x, sa.y), fmaxf(sa.z, sa.w)),
                        fmaxf(fmaxf(sb.x, sb.y), fmaxf(sb.z, sb.w)));
        m = wave_max(m);
        if ((tid & 63) == 0) red[tid >> 6] = m;
        __syncthreads();
        if (tid == 0) bM = fmaxf(fmaxf(red[0], red[1]), fmaxf(red[2], red[3]));
        __syncthreads();
        float M = bM;
        float e = expf(sa.x - M) + expf(sa.y - M) + expf(sa.z - M) + expf(sa.w - M)
                + expf(sb.x - M) + expf(sb.y - M) + expf(sb.z - M) + expf(sb.w - M);
        e = wave_sum(e);
        if ((tid & 63) == 0) red[tid >> 6] = e;
        __syncthreads();
        if (tid == 0) bS = red[0] + red[1] + red[2] + red[3];
        __syncthreads();
        float inv = 1.f / bS;

        int sbase = b * 8;
        if (tid < 8) {
            float wt = expf(ws_scores[sbase + tid] - M) * inv;
            w_lds[tid] = wt;
            out_w[sbase + tid] = wt;
        }
        __syncthreads();

        int e4 = tid * 4;
        float a0 = 0.f, a1 = 0.f, a2 = 0.f, a3 = 0.f;
        #pragma unroll
        for (int i = 0; i < 8; ++i) {
            float wt = w_lds[i];
            float4 ev = *(const float4*)(enc + (size_t)(sbase + i) * E_DIM + e4);
            a0 += wt * ev.x; a1 += wt * ev.y; a2 += wt * ev.z; a3 += wt * ev.w;
        }
        atomicAdd(&ws_ctx[e4 + 0], a0);
        atomicAdd(&ws_ctx[e4 + 1], a1);
        atomicAdd(&ws_ctx[e4 + 2], a2);
        atomicAdd(&ws_ctx[e4 + 3], a3);
    }

    grid_bar(bar, 768);

    // ================= phase 4: x_t = tanh(W_ah @ [ctx; h] + b_ah) ======
    {
        const float* ws_ctx = wsf + WS_CTX;
        int w = tid >> 6, l = tid & 63;
        int r = b * 4 + w;
        const float* wrow = W_ah + (size_t)r * (E_DIM + H_DIM);
        int c4 = l * 4;
        float s = 0.f;
        #pragma unroll
        for (int it = 0; it < 4; ++it) {
            int col = it * 256 + c4;
            s += dot4(*(const float4*)(wrow + col), *(const float4*)(ws_ctx + col));
            s += dot4(*(const float4*)(wrow + 1024 + col), *(const float4*)(out_h + col));
        }
        s = wave_sum(s);
        if (l == 0) out_xt[r] = tanhf(s + b_ah[r]);
    }
}

// ---------------- K3: logits + exp-sum (no max subtraction) -------------
// |logit| bounded (~3) with 0.02-scale weights -> fp32-safe with M=0.
// wave = 4 rows; grid 2000 x 256 (16 rows/block)
__global__ __launch_bounds__(256) void k_logits(
    const float* __restrict__ W_out, const float* __restrict__ b_out,
    const float* __restrict__ out_xt,
    float* __restrict__ out_log, float* __restrict__ ws_expsum)
{
    __shared__ float red[4];
    int tid = threadIdx.x;
    int w = tid >> 6, l = tid & 63;
    int sub = l >> 4, l16 = l & 15;
    int row = blockIdx.x * 16 + w * 4 + sub;
    const float* wrow = W_out + (size_t)row * H_DIM;
    int c4 = l16 * 4;
    float s = 0.f;
    #pragma unroll 4
    for (int it = 0; it < 16; ++it) {
        int col = it * 64 + c4;
        s += dot4(*(const float4*)(wrow + col), *(const float4*)(out_xt + col));
    }
    s = red16_sum(s);
    float lg = s + b_out[row];
    float e = 0.f;
    if (l16 == 0) { out_log[row] = lg; e = expf(lg); }
    e = wave_sum(e);
    if (l == 0) red[w] = e;
    __syncthreads();
    if (tid == 0)
        atomicAdd(ws_expsum, red[0] + red[1] + red[2] + red[3]);
}

// ---------------- K4: out_log -= log(expsum) ----------------------------
__global__ __launch_bounds__(256) void k_writeout(
    const float* __restrict__ ws_expsum, float* __restrict__ out_log)
{
    int i = blockIdx.x * 256 + threadIdx.x;
    float lz = logf(ws_expsum[0]);
    out_log[i] = out_log[i] - lz;
}

extern "C" void kernel_launch(void* const* d_in, const int* in_sizes, int n_in,
                              void* d_out, int out_size, void* d_ws, size_t ws_size,
                              hipStream_t stream) {
    const float* enc      = (const float*)d_in[0];
    const int*   word     = (const int*)d_in[1];
    const float* last_ctx = (const float*)d_in[2];
    const float* h0       = (const float*)d_in[3];
    const float* c0       = (const float*)d_in[4];
    const float* emb      = (const float*)d_in[5];
    const float* W_ih     = (const float*)d_in[6];
    const float* b_ih     = (const float*)d_in[7];
    const float* W_hh     = (const float*)d_in[8];
    const float* b_hh     = (const float*)d_in[9];
    const float* W_att    = (const float*)d_in[10];
    const float* b_att    = (const float*)d_in[11];
    const float* vvec     = (const float*)d_in[12];
    const float* W_ah     = (const float*)d_in[13];
    const float* b_ah     = (const float*)d_in[14];
    const float* W_out    = (const float*)d_in[15];
    const float* b_out    = (const float*)d_in[16];

    float* wsf = (float*)d_ws;

    float* out     = (float*)d_out;
    float* out_log = out + OUT_LOG;
    float* out_h   = out + OUT_H;
    float* out_c   = out + OUT_C;
    float* out_xt  = out + OUT_XT;
    float* out_w   = out + OUT_W;

    k_lstm<<<1024, 256, 0, stream>>>(last_ctx, word, emb, h0, c0,
                                     W_ih, b_ih, W_hh, b_hh, out_h, out_c, wsf);
    k_att_fused<<<256, 256, 0, stream>>>(W_att, b_att, out_h, enc, vvec,
                                         W_ah, b_ah, out_w, out_xt, wsf);
    k_logits<<<2000, 256, 0, stream>>>(W_out, b_out, out_xt,
                                       out_log, wsf + WS_EXPSUM);
    k_writeout<<<125, 256, 0, stream>>>(wsf + WS_EXPSUM, out_log);
}

// Round 13
// 360.027 us; speedup vs baseline: 1.4902x; 1.4902x over previous
//
#include <hip/hip_runtime.h>
#include <math.h>

typedef unsigned short u16;
typedef unsigned int u32;

typedef float  floatx4 __attribute__((ext_vector_type(4)));
typedef short  shortx8 __attribute__((ext_vector_type(8)));

#define S_LEN 2048
#define E_DIM 1024
#define H_DIM 1024
#define V_DIM 32000

// d_out offsets (fp32 elements)
#define OUT_LOG 0
#define OUT_H   32000
#define OUT_C   33024
#define OUT_XT  34048
#define OUT_W   35072

// ws layout (floats)
#define WS_UB     0
#define WS_SCORES 1024
#define WS_CTX    3072
#define WS_EXPSUM 4097
#define WS_ENC16  4608                    // 2048x1024 bf16 = 1048576 floats
#define WS_W16    (4608 + 1048576)       // 1024x1024 bf16 = 524288 floats

__device__ __forceinline__ u16 f2bf_fast(float f) {
    union { float f; u32 i; } v; v.f = f;
    return (u16)((v.i + 0x8000u) >> 16);
}
__device__ __forceinline__ float red16_sum(float x) {
    #pragma unroll
    for (int m = 1; m <= 8; m <<= 1) x += __shfl_xor(x, m, 64);
    return x;
}
__device__ __forceinline__ float wave_sum(float x) {
    #pragma unroll
    for (int m = 32; m >= 1; m >>= 1) x += __shfl_xor(x, m, 64);
    return x;
}
__device__ __forceinline__ float wave_max(float x) {
    #pragma unroll
    for (int m = 32; m >= 1; m >>= 1) x = fmaxf(x, __shfl_xor(x, m, 64));
    return x;
}
__device__ __forceinline__ float dot4(float4 a, float4 b) {
    return a.x * b.x + a.y * b.y + a.z * b.z + a.w * b.w;
}
__device__ __forceinline__ void cvt8(u16* t, float4 a, float4 b) {
    t[0] = f2bf_fast(a.x); t[1] = f2bf_fast(a.y);
    t[2] = f2bf_fast(a.z); t[3] = f2bf_fast(a.w);
    t[4] = f2bf_fast(b.x); t[5] = f2bf_fast(b.y);
    t[6] = f2bf_fast(b.z); t[7] = f2bf_fast(b.w);
}

// ---------------- K1: LSTM cell -----------------------------------------
// block = one hidden unit j; wave g = gate row g*H+j, full 64-lane dot.
// grid 1024 x 256 -> 16 waves/CU.
__global__ __launch_bounds__(256) void k_lstm(
    const float* __restrict__ last_ctx, const int* __restrict__ word,
    const float* __restrict__ emb, const float* __restrict__ h0,
    const float* __restrict__ c0,
    const float* __restrict__ W_ih, const float* __restrict__ b_ih,
    const float* __restrict__ W_hh, const float* __restrict__ b_hh,
    float* __restrict__ out_h, float* __restrict__ out_c)
{
    __shared__ float gsh[4];
    int tid = threadIdx.x;
    int g = tid >> 6, l = tid & 63;
    int j = blockIdx.x;
    int row = g * H_DIM + j;
    const float* embrow = emb + (size_t)word[0] * E_DIM;
    const float* wrow = W_ih + (size_t)row * (E_DIM + H_DIM);
    const float* hrow = W_hh + (size_t)row * H_DIM;
    int c4 = l * 4;

    float s = 0.f;
    #pragma unroll
    for (int it = 0; it < 4; ++it) {            // lstm_in cols [0,1024): last_ctx
        int col = it * 256 + c4;
        s += dot4(*(const float4*)(wrow + col), *(const float4*)(last_ctx + col));
    }
    #pragma unroll
    for (int it = 0; it < 4; ++it) {            // lstm_in cols [1024,2048): emb
        int col = it * 256 + c4;
        s += dot4(*(const float4*)(wrow + 1024 + col), *(const float4*)(embrow + col));
    }
    #pragma unroll
    for (int it = 0; it < 4; ++it) {            // W_hh @ h0
        int col = it * 256 + c4;
        s += dot4(*(const float4*)(hrow + col), *(const float4*)(h0 + col));
    }
    s = wave_sum(s);
    if (l == 0) gsh[g] = s + b_ih[row] + b_hh[row];
    __syncthreads();
    if (tid == 0) {
        float gi = 1.f / (1.f + expf(-gsh[0]));
        float gf = 1.f / (1.f + expf(-gsh[1]));
        float gg = tanhf(gsh[2]);
        float go = 1.f / (1.f + expf(-gsh[3]));
        float c = gf * c0[j] + gi * gg;
        float h = go * tanhf(c);
        out_h[j] = h;
        out_c[j] = c;
    }
}

// ---------------- K2: ub rows + zero scratch + bf16 pre-pack -------------
// grid 256 x 256. Per block: 4 ub rows (full-wave dots), 8 enc rows and
// 4 W_att e-half rows converted to bf16 in ws.
__global__ __launch_bounds__(256) void k_uproj(
    const float* __restrict__ W_att, const float* __restrict__ b_att,
    const float* __restrict__ out_h, const float* __restrict__ enc,
    float* __restrict__ wsf)
{
    int tid = threadIdx.x;
    int b = blockIdx.x;
    int gid = b * 256 + tid;
    if (gid < S_LEN) wsf[WS_SCORES + gid] = 0.f;
    else if (gid < S_LEN + E_DIM) wsf[WS_CTX + gid - S_LEN] = 0.f;
    else if (gid == S_LEN + E_DIM) wsf[WS_EXPSUM] = 0.f;

    // ub[r] = b_att[r] + W_att[r,0:H] @ h
    int w = tid >> 6, l = tid & 63;
    int r = b * 4 + w;
    const float* wrow = W_att + (size_t)r * (E_DIM + H_DIM);
    int c4 = l * 4;
    float s = 0.f;
    #pragma unroll
    for (int it = 0; it < 4; ++it) {
        int col = it * 256 + c4;
        s += dot4(*(const float4*)(wrow + col), *(const float4*)(out_h + col));
    }
    s = wave_sum(s);
    if (l == 0) wsf[WS_UB + r] = s + b_att[r];

    u16* enc16 = (u16*)(wsf + WS_ENC16);
    u16* w16   = (u16*)(wsf + WS_W16);
    {   // enc -> bf16: 8 rows/block, 32 floats/thread
        int row = b * 8 + (tid >> 5);
        int col = (tid & 31) * 32;
        const float* src = enc + (size_t)row * E_DIM + col;
        u16 t[32];
        #pragma unroll
        for (int m = 0; m < 32; m += 8) {
            float4 x = *(const float4*)(src + m);
            float4 y = *(const float4*)(src + m + 4);
            cvt8(t + m, x, y);
        }
        uint4* dst = (uint4*)(enc16 + (size_t)row * E_DIM + col);
        #pragma unroll
        for (int m = 0; m < 4; ++m) dst[m] = *(uint4*)(t + m * 8);
    }
    {   // W_att[:, H:H+E] -> bf16: 4 rows/block, 16 floats/thread
        int row = b * 4 + (tid >> 6);
        int col = (tid & 63) * 16;
        const float* src = W_att + (size_t)row * (E_DIM + H_DIM) + H_DIM + col;
        u16 t[16];
        float4 x0 = *(const float4*)(src);
        float4 x1 = *(const float4*)(src + 4);
        float4 x2 = *(const float4*)(src + 8);
        float4 x3 = *(const float4*)(src + 12);
        cvt8(t, x0, x1); cvt8(t + 8, x2, x3);
        uint4* dst = (uint4*)(w16 + (size_t)row * E_DIM + col);
        dst[0] = *(uint4*)(t);
        dst[1] = *(uint4*)(t + 8);
    }
}

// ---------------- K3: fused scores GEMM (bf16, 64x64 tiles) --------------
// scores[s] = sum_r v[r] * tanh( ub[r] + sum_e enc[s,e]*W_att[r,H+e] )
// tile 64s x 64r; grid 32 s-blocks x 16 r-blocks = 512 blocks
//   -> 2 blocks/CU, 8 waves/CU (was 1 block / 4 waves: latency-exposed).
// Wave w computes rows s0+w*16..+16 x all 64 r. Double-buffered LDS,
// issue-early loads; staging: waves 0-1 stage A, waves 2-3 stage B.
#define LDS_P 40
__global__ __launch_bounds__(256) void k_att_scores(
    const u16* __restrict__ enc16, const u16* __restrict__ w16,
    const float* __restrict__ vvec, const float* __restrict__ ws_ub,
    float* __restrict__ ws_scores)
{
    __shared__ u16 lds_a[2][64 * LDS_P];   // enc tile: 64 s x 32 e
    __shared__ u16 lds_b[2][64 * LDS_P];   // W tile:  64 r x 32 e

    int tid = threadIdx.x;
    int w = tid >> 6, l = tid & 63;
    int b = blockIdx.x;
    int s0 = (b & 31) * 64;
    int r0 = (b >> 5) * 64;
    int lrow = l & 15, lq = l >> 4;

    // staging: 128 threads per matrix half, 2 thr/row, 16 u16 each
    int half = tid >> 7;                  // 0: A (enc16), 1: B (w16)
    int t128 = tid & 127;
    int srow = t128 >> 1;
    int scol = (t128 & 1) * 16;
    const u16* pbase = half == 0
        ? enc16 + (size_t)(s0 + srow) * E_DIM + scol
        : w16   + (size_t)(r0 + srow) * E_DIM + scol;
    u16* dst[2];
    dst[0] = half == 0 ? &lds_a[0][srow * LDS_P + scol] : &lds_b[0][srow * LDS_P + scol];
    dst[1] = half == 0 ? &lds_a[1][srow * LDS_P + scol] : &lds_b[1][srow * LDS_P + scol];

    floatx4 acc[4];
    #pragma unroll
    for (int i = 0; i < 4; ++i) acc[i] = (floatx4)0.f;

    // prologue: stage chunk 0 into buffer 0
    {
        uint4 v0 = *(const uint4*)(pbase);
        uint4 v1 = *(const uint4*)(pbase + 8);
        *(uint4*)(dst[0])     = v0;
        *(uint4*)(dst[0] + 8) = v1;
    }
    __syncthreads();

    int cur = 0;
    for (int kc = 0; kc < 32; ++kc) {
        uint4 n0, n1;
        if (kc < 31) {                       // issue next-chunk loads EARLY
            const u16* p = pbase + (kc + 1) * 32;
            n0 = *(const uint4*)(p);
            n1 = *(const uint4*)(p + 8);
        }

        shortx8 afrag = *(const shortx8*)&lds_a[cur][(w * 16 + lrow) * LDS_P + lq * 8];
        #pragma unroll
        for (int rc = 0; rc < 4; ++rc) {
            shortx8 bfrag = *(const shortx8*)&lds_b[cur][(rc * 16 + lrow) * LDS_P + lq * 8];
            acc[rc] = __builtin_amdgcn_mfma_f32_16x16x32_bf16(afrag, bfrag, acc[rc], 0, 0, 0);
        }

        if (kc < 31) {                       // write into other buffer
            int nb = cur ^ 1;
            *(uint4*)(dst[nb])     = n0;
            *(uint4*)(dst[nb] + 8) = n1;
        }
        __syncthreads();
        cur ^= 1;
    }

    // C layout: col = lane&15 (r), row = (lane>>4)*4 + reg (s)
    float part[4] = {0.f, 0.f, 0.f, 0.f};
    #pragma unroll
    for (int rc = 0; rc < 4; ++rc) {
        int r = r0 + rc * 16 + lrow;
        float ubr = ws_ub[r];
        float vr  = vvec[r];
        #pragma unroll
        for (int reg = 0; reg < 4; ++reg)
            part[reg] += tanhf(acc[rc][reg] + ubr) * vr;
    }
    #pragma unroll
    for (int m = 1; m <= 8; m <<= 1)
        #pragma unroll
        for (int reg = 0; reg < 4; ++reg)
            part[reg] += __shfl_xor(part[reg], m, 64);
    if (lrow == 0) {
        int sbase = s0 + w * 16 + lq * 4;
        #pragma unroll
        for (int reg = 0; reg < 4; ++reg)
            atomicAdd(&ws_scores[sbase + reg], part[reg]);
    }
}

// ---------------- K4: fused softmax + context ---------------------------
// grid 128 x 256: every block redundantly reduces the 2048 scores (8 KB),
// then computes its 16-s slice of context = w @ enc.
__global__ __launch_bounds__(256) void k_ctx(
    const float* __restrict__ enc, const float* __restrict__ ws_scores,
    float* __restrict__ out_w, float* __restrict__ ws_ctx)
{
    __shared__ float red[4];
    __shared__ float w_lds[16];
    __shared__ float bM, bS;
    int tid = threadIdx.x, b = blockIdx.x;

    float4 sa = *(const float4*)(ws_scores + tid * 8);
    float4 sb = *(const float4*)(ws_scores + tid * 8 + 4);
    float m = fmaxf(fmaxf(fmaxf(sa.x, sa.y), fmaxf(sa.z, sa.w)),
                    fmaxf(fmaxf(sb.x, sb.y), fmaxf(sb.z, sb.w)));
    m = wave_max(m);
    if ((tid & 63) == 0) red[tid >> 6] = m;
    __syncthreads();
    if (tid == 0) bM = fmaxf(fmaxf(red[0], red[1]), fmaxf(red[2], red[3]));
    __syncthreads();
    float M = bM;
    float e = expf(sa.x - M) + expf(sa.y - M) + expf(sa.z - M) + expf(sa.w - M)
            + expf(sb.x - M) + expf(sb.y - M) + expf(sb.z - M) + expf(sb.w - M);
    e = wave_sum(e);
    if ((tid & 63) == 0) red[tid >> 6] = e;
    __syncthreads();
    if (tid == 0) bS = red[0] + red[1] + red[2] + red[3];
    __syncthreads();
    float inv = 1.f / bS;

    int sbase = b * 16;
    if (tid < 16) {
        float wt = expf(ws_scores[sbase + tid] - M) * inv;
        w_lds[tid] = wt;
        out_w[sbase + tid] = wt;
    }
    __syncthreads();

    int e4 = tid * 4;
    float a0 = 0.f, a1 = 0.f, a2 = 0.f, a3 = 0.f;
    #pragma unroll 4
    for (int i = 0; i < 16; ++i) {
        float wt = w_lds[i];
        float4 ev = *(const float4*)(enc + (size_t)(sbase + i) * E_DIM + e4);
        a0 += wt * ev.x; a1 += wt * ev.y; a2 += wt * ev.z; a3 += wt * ev.w;
    }
    atomicAdd(&ws_ctx[e4 + 0], a0);
    atomicAdd(&ws_ctx[e4 + 1], a1);
    atomicAdd(&ws_ctx[e4 + 2], a2);
    atomicAdd(&ws_ctx[e4 + 3], a3);
}

// ---------------- K5: x_t = tanh(W_ah @ [ctx; h] + b_ah) ----------------
// wave = one row (full 64-lane dot); grid 256 x 256
__global__ __launch_bounds__(256) void k_xt(
    const float* __restrict__ W_ah, const float* __restrict__ b_ah,
    const float* __restrict__ ws_ctx, const float* __restrict__ out_h,
    float* __restrict__ out_xt)
{
    int tid = threadIdx.x;
    int w = tid >> 6, l = tid & 63;
    int r = blockIdx.x * 4 + w;
    const float* wrow = W_ah + (size_t)r * (E_DIM + H_DIM);
    int c4 = l * 4;
    float s = 0.f;
    #pragma unroll
    for (int it = 0; it < 4; ++it) {
        int col = it * 256 + c4;
        s += dot4(*(const float4*)(wrow + col), *(const float4*)(ws_ctx + col));
        s += dot4(*(const float4*)(wrow + 1024 + col), *(const float4*)(out_h + col));
    }
    s = wave_sum(s);
    if (l == 0) out_xt[r] = tanhf(s + b_ah[r]);
}

// ---------------- K6: logits + exp-sum (no max subtraction) -------------
// |logit| bounded (~3) with 0.02-scale weights -> fp32-safe with M=0.
// wave = 4 rows; grid 2000 x 256 (16 rows/block)
__global__ __launch_bounds__(256) void k_logits(
    const float* __restrict__ W_out, const float* __restrict__ b_out,
    const float* __restrict__ out_xt,
    float* __restrict__ out_log, float* __restrict__ ws_expsum)
{
    __shared__ float red[4];
    int tid = threadIdx.x;
    int w = tid >> 6, l = tid & 63;
    int sub = l >> 4, l16 = l & 15;
    int row = blockIdx.x * 16 + w * 4 + sub;
    const float* wrow = W_out + (size_t)row * H_DIM;
    int c4 = l16 * 4;
    float s = 0.f;
    #pragma unroll 4
    for (int it = 0; it < 16; ++it) {
        int col = it * 64 + c4;
        s += dot4(*(const float4*)(wrow + col), *(const float4*)(out_xt + col));
    }
    s = red16_sum(s);
    float lg = s + b_out[row];
    float e = 0.f;
    if (l16 == 0) { out_log[row] = lg; e = expf(lg); }
    e = wave_sum(e);
    if (l == 0) red[w] = e;
    __syncthreads();
    if (tid == 0)
        atomicAdd(ws_expsum, red[0] + red[1] + red[2] + red[3]);
}

// ---------------- K7: out_log -= log(expsum) ----------------------------
__global__ __launch_bounds__(256) void k_writeout(
    const float* __restrict__ ws_expsum, float* __restrict__ out_log)
{
    int i = blockIdx.x * 256 + threadIdx.x;
    float lz = logf(ws_expsum[0]);
    out_log[i] = out_log[i] - lz;
}

extern "C" void kernel_launch(void* const* d_in, const int* in_sizes, int n_in,
                              void* d_out, int out_size, void* d_ws, size_t ws_size,
                              hipStream_t stream) {
    const float* enc      = (const float*)d_in[0];
    const int*   word     = (const int*)d_in[1];
    const float* last_ctx = (const float*)d_in[2];
    const float* h0       = (const float*)d_in[3];
    const float* c0       = (const float*)d_in[4];
    const float* emb      = (const float*)d_in[5];
    const float* W_ih     = (const float*)d_in[6];
    const float* b_ih     = (const float*)d_in[7];
    const float* W_hh     = (const float*)d_in[8];
    const float* b_hh     = (const float*)d_in[9];
    const float* W_att    = (const float*)d_in[10];
    const float* b_att    = (const float*)d_in[11];
    const float* vvec     = (const float*)d_in[12];
    const float* W_ah     = (const float*)d_in[13];
    const float* b_ah     = (const float*)d_in[14];
    const float* W_out    = (const float*)d_in[15];
    const float* b_out    = (const float*)d_in[16];

    float* wsf = (float*)d_ws;

    float* out     = (float*)d_out;
    float* out_log = out + OUT_LOG;
    float* out_h   = out + OUT_H;
    float* out_c   = out + OUT_C;
    float* out_xt  = out + OUT_XT;
    float* out_w   = out + OUT_W;

    k_lstm<<<1024, 256, 0, stream>>>(last_ctx, word, emb, h0, c0,
                                     W_ih, b_ih, W_hh, b_hh, out_h, out_c);
    k_uproj<<<256, 256, 0, stream>>>(W_att, b_att, out_h, enc, wsf);
    k_att_scores<<<512, 256, 0, stream>>>((const u16*)(wsf + WS_ENC16),
                                          (const u16*)(wsf + WS_W16),
                                          vvec, wsf + WS_UB, wsf + WS_SCORES);
    k_ctx<<<128, 256, 0, stream>>>(enc, wsf + WS_SCORES, out_w, wsf + WS_CTX);
    k_xt<<<256, 256, 0, stream>>>(W_ah, b_ah, wsf + WS_CTX, out_h, out_xt);
    k_logits<<<2000, 256, 0, stream>>>(W_out, b_out, out_xt,
                                       out_log, wsf + WS_EXPSUM);
    k_writeout<<<125, 256, 0, stream>>>(wsf + WS_EXPSUM, out_log);
}

// Round 15
// 358.136 us; speedup vs baseline: 1.4981x; 1.0053x over previous
//
#include <hip/hip_runtime.h>
#include <math.h>

typedef unsigned short u16;
typedef unsigned int u32;

typedef float  floatx4 __attribute__((ext_vector_type(4)));
typedef short  shortx8 __attribute__((ext_vector_type(8)));

#define S_LEN 2048
#define E_DIM 1024
#define H_DIM 1024
#define V_DIM 32000

// d_out offsets (fp32 elements)
#define OUT_LOG 0
#define OUT_H   32000
#define OUT_C   33024
#define OUT_XT  34048
#define OUT_W   35072

// ws layout (floats)
#define WS_UB     0
#define WS_CTX    1024
#define WS_EXPSUM 2048
#define WS_PART   2560                   // 16 rb x 2048 s = 32768 floats
#define WS_ENC16  35840                  // 2048x1024 bf16 = 1048576 float slots
#define WS_W16    (35840 + 1048576)      // 1024x1024 bf16 = 524288 float slots

__device__ __forceinline__ u16 f2bf_fast(float f) {
    union { float f; u32 i; } v; v.f = f;
    return (u16)((v.i + 0x8000u) >> 16);
}
__device__ __forceinline__ float red16_sum(float x) {
    #pragma unroll
    for (int m = 1; m <= 8; m <<= 1) x += __shfl_xor(x, m, 64);
    return x;
}
__device__ __forceinline__ float wave_sum(float x) {
    #pragma unroll
    for (int m = 32; m >= 1; m >>= 1) x += __shfl_xor(x, m, 64);
    return x;
}
__device__ __forceinline__ float wave_max(float x) {
    #pragma unroll
    for (int m = 32; m >= 1; m >>= 1) x = fmaxf(x, __shfl_xor(x, m, 64));
    return x;
}
__device__ __forceinline__ float dot4(float4 a, float4 b) {
    return a.x * b.x + a.y * b.y + a.z * b.z + a.w * b.w;
}
__device__ __forceinline__ void cvt8(u16* t, float4 a, float4 b) {
    t[0] = f2bf_fast(a.x); t[1] = f2bf_fast(a.y);
    t[2] = f2bf_fast(a.z); t[3] = f2bf_fast(a.w);
    t[4] = f2bf_fast(b.x); t[5] = f2bf_fast(b.y);
    t[6] = f2bf_fast(b.z); t[7] = f2bf_fast(b.w);
}

// ---------------- K1: LSTM cell + bf16 pre-pack --------------------------
// block = one hidden unit j; wave g = gate row g*H+j, full 64-lane dot.
// grid 1024 x 256 -> 16 waves/CU. Also packs enc rows 2j,2j+1 and
// W_att[j, H:H+E] to bf16 (independent of h; contiguous 32B/thread).
__global__ __launch_bounds__(256) void k_lstm(
    const float* __restrict__ last_ctx, const int* __restrict__ word,
    const float* __restrict__ emb, const float* __restrict__ h0,
    const float* __restrict__ c0,
    const float* __restrict__ W_ih, const float* __restrict__ b_ih,
    const float* __restrict__ W_hh, const float* __restrict__ b_hh,
    const float* __restrict__ W_att, const float* __restrict__ enc,
    float* __restrict__ out_h, float* __restrict__ out_c,
    float* __restrict__ wsf)
{
    __shared__ float gsh[4];
    int tid = threadIdx.x;
    int g = tid >> 6, l = tid & 63;
    int j = blockIdx.x;
    int row = g * H_DIM + j;
    const float* embrow = emb + (size_t)word[0] * E_DIM;
    const float* wrow = W_ih + (size_t)row * (E_DIM + H_DIM);
    const float* hrow = W_hh + (size_t)row * H_DIM;
    int c4 = l * 4;

    float s = 0.f;
    #pragma unroll
    for (int it = 0; it < 4; ++it) {            // lstm_in cols [0,1024): last_ctx
        int col = it * 256 + c4;
        s += dot4(*(const float4*)(wrow + col), *(const float4*)(last_ctx + col));
    }
    #pragma unroll
    for (int it = 0; it < 4; ++it) {            // lstm_in cols [1024,2048): emb
        int col = it * 256 + c4;
        s += dot4(*(const float4*)(wrow + 1024 + col), *(const float4*)(embrow + col));
    }
    #pragma unroll
    for (int it = 0; it < 4; ++it) {            // W_hh @ h0
        int col = it * 256 + c4;
        s += dot4(*(const float4*)(hrow + col), *(const float4*)(h0 + col));
    }
    s = wave_sum(s);
    if (l == 0) gsh[g] = s + b_ih[row] + b_hh[row];

    // ---- bf16 pre-pack (no sync needed; independent of gates) ----
    u16* enc16 = (u16*)(wsf + WS_ENC16);
    u16* w16   = (u16*)(wsf + WS_W16);
    {   // enc rows 2j, 2j+1: 128 thr/row, 8 floats (32B) each, contiguous
        int prow = 2 * j + (tid >> 7);
        int pcol = (tid & 127) * 8;
        const float* src = enc + (size_t)prow * E_DIM + pcol;
        float4 x = *(const float4*)(src);
        float4 y = *(const float4*)(src + 4);
        u16 t[8];
        cvt8(t, x, y);
        *(uint4*)(enc16 + (size_t)prow * E_DIM + pcol) = *(uint4*)t;
    }
    {   // W_att[j, H:H+E]: 256 thr x 4 floats (16B) each, contiguous
        int pcol = tid * 4;
        const float* src = W_att + (size_t)j * (E_DIM + H_DIM) + H_DIM + pcol;
        float4 x = *(const float4*)(src);
        u16 t[4];
        t[0] = f2bf_fast(x.x); t[1] = f2bf_fast(x.y);
        t[2] = f2bf_fast(x.z); t[3] = f2bf_fast(x.w);
        *(uint2*)(w16 + (size_t)j * E_DIM + pcol) = *(uint2*)t;
    }

    __syncthreads();
    if (tid == 0) {
        float gi = 1.f / (1.f + expf(-gsh[0]));
        float gf = 1.f / (1.f + expf(-gsh[1]));
        float gg = tanhf(gsh[2]);
        float go = 1.f / (1.f + expf(-gsh[3]));
        float c = gf * c0[j] + gi * gg;
        float h = go * tanhf(c);
        out_h[j] = h;
        out_c[j] = c;
    }
}

// ---------------- K2: ub rows + zero ctx/expsum --------------------------
// grid 256 x 256. Per block: 4 ub rows (full-wave dots).
__global__ __launch_bounds__(256) void k_uproj(
    const float* __restrict__ W_att, const float* __restrict__ b_att,
    const float* __restrict__ out_h, float* __restrict__ wsf)
{
    int tid = threadIdx.x;
    int b = blockIdx.x;
    int gid = b * 256 + tid;
    if (gid < E_DIM) wsf[WS_CTX + gid] = 0.f;
    else if (gid == E_DIM) wsf[WS_EXPSUM] = 0.f;

    int w = tid >> 6, l = tid & 63;
    int r = b * 4 + w;
    const float* wrow = W_att + (size_t)r * (E_DIM + H_DIM);
    int c4 = l * 4;
    float s = 0.f;
    #pragma unroll
    for (int it = 0; it < 4; ++it) {
        int col = it * 256 + c4;
        s += dot4(*(const float4*)(wrow + col), *(const float4*)(out_h + col));
    }
    s = wave_sum(s);
    if (l == 0) wsf[WS_UB + r] = s + b_att[r];
}

// ---------------- K3: fused scores GEMM (bf16, 64x64 tiles) --------------
// partial[rb][s] = sum_{r in rb} v[r] * tanh( ub[r] + enc[s,:]@W_att[r,H:] )
// tile 64s x 64r; grid 32 s-blocks x 16 r-blocks = 512 blocks.
// Plain stores (unique (rb,s) per lane) -- no atomics, no pre-zero.
#define LDS_P 40
__global__ __launch_bounds__(256) void k_att_scores(
    const u16* __restrict__ enc16, const u16* __restrict__ w16,
    const float* __restrict__ vvec, const float* __restrict__ ws_ub,
    float* __restrict__ ws_part)
{
    __shared__ u16 lds_a[2][64 * LDS_P];   // enc tile: 64 s x 32 e
    __shared__ u16 lds_b[2][64 * LDS_P];   // W tile:  64 r x 32 e

    int tid = threadIdx.x;
    int w = tid >> 6, l = tid & 63;
    int b = blockIdx.x;
    int s0 = (b & 31) * 64;
    int r0 = (b >> 5) * 64;
    int lrow = l & 15, lq = l >> 4;

    // staging: 128 threads per matrix half, 2 thr/row, 16 u16 each
    int half = tid >> 7;                  // 0: A (enc16), 1: B (w16)
    int t128 = tid & 127;
    int srow = t128 >> 1;
    int scol = (t128 & 1) * 16;
    const u16* pbase = half == 0
        ? enc16 + (size_t)(s0 + srow) * E_DIM + scol
        : w16   + (size_t)(r0 + srow) * E_DIM + scol;
    u16* dst[2];
    dst[0] = half == 0 ? &lds_a[0][srow * LDS_P + scol] : &lds_b[0][srow * LDS_P + scol];
    dst[1] = half == 0 ? &lds_a[1][srow * LDS_P + scol] : &lds_b[1][srow * LDS_P + scol];

    floatx4 acc[4];
    #pragma unroll
    for (int i = 0; i < 4; ++i) acc[i] = (floatx4)0.f;

    // prologue: stage chunk 0 into buffer 0
    {
        uint4 v0 = *(const uint4*)(pbase);
        uint4 v1 = *(const uint4*)(pbase + 8);
        *(uint4*)(dst[0])     = v0;
        *(uint4*)(dst[0] + 8) = v1;
    }
    __syncthreads();

    int cur = 0;
    for (int kc = 0; kc < 32; ++kc) {
        uint4 n0, n1;
        if (kc < 31) {                       // issue next-chunk loads EARLY
            const u16* p = pbase + (kc + 1) * 32;
            n0 = *(const uint4*)(p);
            n1 = *(const uint4*)(p + 8);
        }

        shortx8 afrag = *(const shortx8*)&lds_a[cur][(w * 16 + lrow) * LDS_P + lq * 8];
        #pragma unroll
        for (int rc = 0; rc < 4; ++rc) {
            shortx8 bfrag = *(const shortx8*)&lds_b[cur][(rc * 16 + lrow) * LDS_P + lq * 8];
            acc[rc] = __builtin_amdgcn_mfma_f32_16x16x32_bf16(afrag, bfrag, acc[rc], 0, 0, 0);
        }

        if (kc < 31) {                       // write into other buffer
            int nb = cur ^ 1;
            *(uint4*)(dst[nb])     = n0;
            *(uint4*)(dst[nb] + 8) = n1;
        }
        __syncthreads();
        cur ^= 1;
    }

    // C layout: col = lane&15 (r), row = (lane>>4)*4 + reg (s)
    float part[4] = {0.f, 0.f, 0.f, 0.f};
    #pragma unroll
    for (int rc = 0; rc < 4; ++rc) {
        int r = r0 + rc * 16 + lrow;
        float ubr = ws_ub[r];
        float vr  = vvec[r];
        #pragma unroll
        for (int reg = 0; reg < 4; ++reg)
            part[reg] += tanhf(acc[rc][reg] + ubr) * vr;
    }
    #pragma unroll
    for (int m = 1; m <= 8; m <<= 1)
        #pragma unroll
        for (int reg = 0; reg < 4; ++reg)
            part[reg] += __shfl_xor(part[reg], m, 64);
    if (lrow == 0) {
        int rb = b >> 5;
        int sbase = s0 + w * 16 + lq * 4;
        #pragma unroll
        for (int reg = 0; reg < 4; ++reg)
            ws_part[rb * S_LEN + sbase + reg] = part[reg];
    }
}

// ---------------- K4: partial-sum + softmax + context --------------------
// grid 128 x 256: every block sums the 16 r-partials into the 2048 scores
// (thread t holds s = t*8..t*8+7), reduces max/sum redundantly, then
// computes its 16-s slice of context = w @ enc.
__global__ __launch_bounds__(256) void k_ctx(
    const float* __restrict__ enc, const float* __restrict__ ws_part,
    float* __restrict__ out_w, float* __restrict__ ws_ctx)
{
    __shared__ float red[4];
    __shared__ float w_lds[16];
    __shared__ float bM, bS;
    int tid = threadIdx.x, b = blockIdx.x;

    float4 sa = {0.f, 0.f, 0.f, 0.f};
    float4 sb = {0.f, 0.f, 0.f, 0.f};
    #pragma unroll
    for (int rb = 0; rb < 16; ++rb) {
        const float* p = ws_part + rb * S_LEN + tid * 8;
        float4 a = *(const float4*)(p);
        float4 c = *(const float4*)(p + 4);
        sa.x += a.x; sa.y += a.y; sa.z += a.z; sa.w += a.w;
        sb.x += c.x; sb.y += c.y; sb.z += c.z; sb.w += c.w;
    }

    float m = fmaxf(fmaxf(fmaxf(sa.x, sa.y), fmaxf(sa.z, sa.w)),
                    fmaxf(fmaxf(sb.x, sb.y), fmaxf(sb.z, sb.w)));
    m = wave_max(m);
    if ((tid & 63) == 0) red[tid >> 6] = m;
    __syncthreads();
    if (tid == 0) bM = fmaxf(fmaxf(red[0], red[1]), fmaxf(red[2], red[3]));
    __syncthreads();
    float M = bM;
    float e = expf(sa.x - M) + expf(sa.y - M) + expf(sa.z - M) + expf(sa.w - M)
            + expf(sb.x - M) + expf(sb.y - M) + expf(sb.z - M) + expf(sb.w - M);
    e = wave_sum(e);
    if ((tid & 63) == 0) red[tid >> 6] = e;
    __syncthreads();
    if (tid == 0) bS = red[0] + red[1] + red[2] + red[3];
    __syncthreads();
    float inv = 1.f / bS;

    // block b's 16 s-rows are held by threads 2b (s: b*16..+7) and 2b+1
    int sbase = b * 16;
    if ((tid >> 1) == b) {
        int off = (tid & 1) * 8;
        float sc[8] = {sa.x, sa.y, sa.z, sa.w, sb.x, sb.y, sb.z, sb.w};
        #pragma unroll
        for (int i = 0; i < 8; ++i) {
            float wt = expf(sc[i] - M) * inv;
            w_lds[off + i] = wt;
            out_w[sbase + off + i] = wt;
        }
    }
    __syncthreads();

    int e4 = tid * 4;
    float a0 = 0.f, a1 = 0.f, a2 = 0.f, a3 = 0.f;
    #pragma unroll 4
    for (int i = 0; i < 16; ++i) {
        float wt = w_lds[i];
        float4 ev = *(const float4*)(enc + (size_t)(sbase + i) * E_DIM + e4);
        a0 += wt * ev.x; a1 += wt * ev.y; a2 += wt * ev.z; a3 += wt * ev.w;
    }
    atomicAdd(&ws_ctx[e4 + 0], a0);
    atomicAdd(&ws_ctx[e4 + 1], a1);
    atomicAdd(&ws_ctx[e4 + 2], a2);
    atomicAdd(&ws_ctx[e4 + 3], a3);
}

// ---------------- K5: x_t = tanh(W_ah @ [ctx; h] + b_ah) ----------------
// wave = one row (full 64-lane dot); grid 256 x 256
__global__ __launch_bounds__(256) void k_xt(
    const float* __restrict__ W_ah, const float* __restrict__ b_ah,
    const float* __restrict__ ws_ctx, const float* __restrict__ out_h,
    float* __restrict__ out_xt)
{
    int tid = threadIdx.x;
    int w = tid >> 6, l = tid & 63;
    int r = blockIdx.x * 4 + w;
    const float* wrow = W_ah + (size_t)r * (E_DIM + H_DIM);
    int c4 = l * 4;
    float s = 0.f;
    #pragma unroll
    for (int it = 0; it < 4; ++it) {
        int col = it * 256 + c4;
        s += dot4(*(const float4*)(wrow + col), *(const float4*)(ws_ctx + col));
        s += dot4(*(const float4*)(wrow + 1024 + col), *(const float4*)(out_h + col));
    }
    s = wave_sum(s);
    if (l == 0) out_xt[r] = tanhf(s + b_ah[r]);
}

// ---------------- K6: logits + exp-sum (no max subtraction) -------------
// |logit| bounded (~3) with 0.02-scale weights -> fp32-safe with M=0.
// wave = 4 rows; grid 2000 x 256 (16 rows/block)
__global__ __launch_bounds__(256) void k_logits(
    const float* __restrict__ W_out, const float* __restrict__ b_out,
    const float* __restrict__ out_xt,
    float* __restrict__ out_log, float* __restrict__ ws_expsum)
{
    __shared__ float red[4];
    int tid = threadIdx.x;
    int w = tid >> 6, l = tid & 63;
    int sub = l >> 4, l16 = l & 15;
    int row = blockIdx.x * 16 + w * 4 + sub;
    const float* wrow = W_out + (size_t)row * H_DIM;
    int c4 = l16 * 4;
    float s = 0.f;
    #pragma unroll 4
    for (int it = 0; it < 16; ++it) {
        int col = it * 64 + c4;
        s += dot4(*(const float4*)(wrow + col), *(const float4*)(out_xt + col));
    }
    s = red16_sum(s);
    float lg = s + b_out[row];
    float e = 0.f;
    if (l16 == 0) { out_log[row] = lg; e = expf(lg); }
    e = wave_sum(e);
    if (l == 0) red[w] = e;
    __syncthreads();
    if (tid == 0)
        atomicAdd(ws_expsum, red[0] + red[1] + red[2] + red[3]);
}

// ---------------- K7: out_log -= log(expsum) ----------------------------
__global__ __launch_bounds__(256) void k_writeout(
    const float* __restrict__ ws_expsum, float* __restrict__ out_log)
{
    int i = blockIdx.x * 256 + threadIdx.x;
    float lz = logf(ws_expsum[0]);
    out_log[i] = out_log[i] - lz;
}

extern "C" void kernel_launch(void* const* d_in, const int* in_sizes, int n_in,
                              void* d_out, int out_size, void* d_ws, size_t ws_size,
                              hipStream_t stream) {
    const float* enc      = (const float*)d_in[0];
    const int*   word     = (const int*)d_in[1];
    const float* last_ctx = (const float*)d_in[2];
    const float* h0       = (const float*)d_in[3];
    const float* c0       = (const float*)d_in[4];
    const float* emb      = (const float*)d_in[5];
    const float* W_ih     = (const float*)d_in[6];
    const float* b_ih     = (const float*)d_in[7];
    const float* W_hh     = (const float*)d_in[8];
    const float* b_hh     = (const float*)d_in[9];
    const float* W_att    = (const float*)d_in[10];
    const float* b_att    = (const float*)d_in[11];
    const float* vvec     = (const float*)d_in[12];
    const float* W_ah     = (const float*)d_in[13];
    const float* b_ah     = (const float*)d_in[14];
    const float* W_out    = (const float*)d_in[15];
    const float* b_out    = (const float*)d_in[16];

    float* wsf = (float*)d_ws;

    float* out     = (float*)d_out;
    float* out_log = out + OUT_LOG;
    float* out_h   = out + OUT_H;
    float* out_c   = out + OUT_C;
    float* out_xt  = out + OUT_XT;
    float* out_w   = out + OUT_W;

    k_lstm<<<1024, 256, 0, stream>>>(last_ctx, word, emb, h0, c0,
                                     W_ih, b_ih, W_hh, b_hh, W_att, enc,
                                     out_h, out_c, wsf);
    k_uproj<<<256, 256, 0, stream>>>(W_att, b_att, out_h, wsf);
    k_att_scores<<<512, 256, 0, stream>>>((const u16*)(wsf + WS_ENC16),
                                          (const u16*)(wsf + WS_W16),
                                          vvec, wsf + WS_UB, wsf + WS_PART);
    k_ctx<<<128, 256, 0, stream>>>(enc, wsf + WS_PART, out_w, wsf + WS_CTX);
    k_xt<<<256, 256, 0, stream>>>(W_ah, b_ah, wsf + WS_CTX, out_h, out_xt);
    k_logits<<<2000, 256, 0, stream>>>(W_out, b_out, out_xt,
                                       out_log, wsf + WS_EXPSUM);
    k_writeout<<<125, 256, 0, stream>>>(wsf + WS_EXPSUM, out_log);
}